// Round 10
// baseline (44.964 us; speedup 1.0000x reference)
//
#include <hip/hip_runtime.h>

// YOLOv3 loss: B=32, A=3, S=52, C=80
constexpr int Aa = 3, Ss = 52, Cc = 80;
constexpr int NCELL = 32 * Aa * Ss * Ss;       // 259584 (divisible by 4)
constexpr int PSTR  = 5 + Cc;                  // 85 floats per cell
constexpr int G     = 4;                       // cells per thread
constexpr float L_CLASS = 1.0f, L_NOOBJ = 10.0f, L_OBJ = 1.0f, L_BOX = 10.0f;

// ---- DPP helpers: row_ror:k butterfly within 16-lane rows ----
__device__ __forceinline__ float dpp_ror1(float x) {
    return __builtin_bit_cast(float, __builtin_amdgcn_update_dpp(
        0, __builtin_bit_cast(int, x), 0x121, 0xf, 0xf, false));
}
__device__ __forceinline__ float dpp_ror2(float x) {
    return __builtin_bit_cast(float, __builtin_amdgcn_update_dpp(
        0, __builtin_bit_cast(int, x), 0x122, 0xf, 0xf, false));
}
__device__ __forceinline__ float dpp_ror4(float x) {
    return __builtin_bit_cast(float, __builtin_amdgcn_update_dpp(
        0, __builtin_bit_cast(int, x), 0x124, 0xf, 0xf, false));
}
__device__ __forceinline__ float dpp_ror8(float x) {
    return __builtin_bit_cast(float, __builtin_amdgcn_update_dpp(
        0, __builtin_bit_cast(int, x), 0x128, 0xf, 0xf, false));
}
__device__ __forceinline__ float wave_sum(float x) {
    x += dpp_ror1(x); x += dpp_ror2(x); x += dpp_ror4(x); x += dpp_ror8(x);
    x += __shfl_xor(x, 16, 64);
    x += __shfl_xor(x, 32, 64);
    return x;
}
__device__ __forceinline__ float wave_max(float x) {
    x = fmaxf(x, dpp_ror1(x)); x = fmaxf(x, dpp_ror2(x));
    x = fmaxf(x, dpp_ror4(x)); x = fmaxf(x, dpp_ror8(x));
    x = fmaxf(x, __shfl_xor(x, 16, 64));
    x = fmaxf(x, __shfl_xor(x, 32, 64));
    return x;
}
__device__ __forceinline__ float rdlane(float v, int l) {
    return __builtin_bit_cast(float, __builtin_amdgcn_readlane(__builtin_bit_cast(int, v), l));
}
__device__ __forceinline__ float bce0_fast(float x) {
    return fmaxf(x, 0.0f) + __logf(1.0f + __expf(-fabsf(x)));
}
__device__ __forceinline__ float pick4(float4 w, unsigned c) {   // c wave-uniform
    return (c == 0u) ? w.x : (c == 1u) ? w.y : (c == 2u) ? w.z : w.w;
}

// advance the flattened (mask0..mask3) iterator; all state wave-uniform
__device__ __forceinline__ bool next_item(unsigned long long& cm, int& gi,
                                          unsigned long long m1, unsigned long long m2,
                                          unsigned long long m3, int& src, int& g) {
    while (true) {
        if (cm) { src = __ffsll(cm) - 1; cm &= cm - 1; g = gi; return true; }
        if (gi >= 3) return false;
        ++gi;
        cm = (gi == 1) ? m1 : (gi == 2) ? m2 : m3;
    }
}

// acc layout: [0]=n_obj [1]=n_noobj [2]=noobj_sum [3]=obj_sum [4]=box_sum [5]=cls_sum
__global__ void __launch_bounds__(256) yolo_main(const float* __restrict__ pred,
                                                 const float4* __restrict__ pred4,
                                                 const float* __restrict__ tgt,
                                                 const float* __restrict__ anchors,
                                                 float* __restrict__ acc) {
    const int lane = threadIdx.x & 63;
    const int wid  = threadIdx.x >> 6;
    const int tid  = blockIdx.x * blockDim.x + threadIdx.x;
    const unsigned wavebase = blockIdx.x * blockDim.x + wid * 64;
    const int base = tid * G;
    const bool valid = base < NCELL;

    // anchors: 6 floats preloaded (L1 broadcast), selected by uniform index later
    const float an0x = anchors[0], an0y = anchors[1];
    const float an1x = anchors[2], an1y = anchors[3];
    const float an2x = anchors[4], an2y = anchors[5];

    float a_nobj = 0.f, a_nnoobj = 0.f, a_noobj = 0.f, a_obj = 0.f, a_box = 0.f, a_cls = 0.f;

    // --- upfront independent loads: 4 scattered p0 + 4 scalar t0 per thread ---
    float p0v[G], t0v[G];
    #pragma unroll
    for (int g = 0; g < G; ++g) { p0v[g] = 0.f; t0v[g] = -1.0f; }
    if (valid) {
        #pragma unroll
        for (int g = 0; g < G; ++g) p0v[g] = pred[(size_t)(base + g) * PSTR];
        #pragma unroll
        for (int g = 0; g < G; ++g) t0v[g] = tgt[(size_t)(base + g) * 6];
    }

    bool obj[G];
    #pragma unroll
    for (int g = 0; g < G; ++g) {
        obj[g] = (t0v[g] == 1.0f);
        if (t0v[g] == 0.0f) {
            a_nnoobj += 1.0f;
            a_noobj  += bce0_fast(p0v[g]);
        }
    }

    const unsigned long long mm0 = __ballot(obj[0]);
    const unsigned long long mm1 = __ballot(obj[1]);
    const unsigned long long mm2 = __ballot(obj[2]);
    const unsigned long long mm3 = __ballot(obj[3]);

    // --- flattened object-cell loop, 2-deep pipelined, 22-lane window reads ---
    unsigned long long cm = mm0;
    int gi = 0, s0, g0;
    if (next_item(cm, gi, mm1, mm2, mm3, s0, g0)) {
        unsigned oc = (wavebase + (unsigned)s0) * 4u + (unsigned)g0;
        float4 w = make_float4(0.f, 0.f, 0.f, 0.f);
        float tv = 0.f;
        if (lane < 22) w = pred4[((85u * oc) >> 2) + (unsigned)lane];
        if (lane >= 32 && lane < 38) tv = tgt[6u * oc + (unsigned)(lane - 32)];

        while (true) {
            // prefetch next item's window + target scalars
            int s1, g1;
            const bool h2 = next_item(cm, gi, mm1, mm2, mm3, s1, g1);
            unsigned oc1 = 0;
            float4 w2 = make_float4(0.f, 0.f, 0.f, 0.f);
            float tv2 = 0.f;
            if (h2) {
                oc1 = (wavebase + (unsigned)s1) * 4u + (unsigned)g1;
                if (lane < 22) w2 = pred4[((85u * oc1) >> 2) + (unsigned)lane];
                if (lane >= 32 && lane < 38) tv2 = tgt[6u * oc1 + (unsigned)(lane - 32)];
            }

            // ---- reduce current item ----
            const unsigned d2 = oc & 3u;              // (85*oc)&3 == oc&3
            const int e0 = 4 * lane;
            float vv[4] = { w.x, w.y, w.z, w.w };
            float lmax = -INFINITY;
            #pragma unroll
            for (int k = 0; k < 4; ++k) {
                const bool vl = (lane < 22) && ((unsigned)(e0 + k) - (d2 + 5u) < 80u);
                lmax = vl ? fmaxf(lmax, vv[k]) : lmax;
            }
            const float mx = wave_max(lmax);
            float lsum = 0.f;
            #pragma unroll
            for (int k = 0; k < 4; ++k) {
                const bool vl = (lane < 22) && ((unsigned)(e0 + k) - (d2 + 5u) < 80u);
                lsum += vl ? __expf(vv[k] - mx) : 0.f;
            }
            const float e = wave_sum(lsum);

            const int   cls = (int)rdlane(tv, 37);    // t[5]
            const unsigned ei = d2 + 5u + (unsigned)cls;
            const float lc = rdlane(pick4(w, ei & 3u), (int)(ei >> 2));

            float pv[5];
            #pragma unroll
            for (int i = 0; i < 5; ++i) {
                const unsigned pi = d2 + (unsigned)i;
                pv[i] = rdlane(pick4(w, pi & 3u), (int)(pi >> 2));
            }
            const float tx = rdlane(tv, 33), ty = rdlane(tv, 34);
            const float tw = rdlane(tv, 35), th = rdlane(tv, 36);

            const unsigned aIdx = (oc / (unsigned)(Ss * Ss)) % 3u;
            const float ax = (aIdx == 0u) ? an0x : (aIdx == 1u) ? an1x : an2x;
            const float ay = (aIdx == 0u) ? an0y : (aIdx == 1u) ? an1y : an2y;

            const float p0 = pv[0];
            const float sx = 1.0f / (1.0f + __expf(-pv[1]));
            const float sy = 1.0f / (1.0f + __expf(-pv[2]));
            const float ew = __expf(pv[3]) * ax;
            const float eh = __expf(pv[4]) * ay;

            const float ax1 = sx - ew * 0.5f, ax2 = sx + ew * 0.5f;
            const float ay1 = sy - eh * 0.5f, ay2 = sy + eh * 0.5f;
            const float bx1 = tx - tw * 0.5f, bx2 = tx + tw * 0.5f;
            const float by1 = ty - th * 0.5f, by2 = ty + th * 0.5f;
            const float iw = fmaxf(fminf(ax2, bx2) - fmaxf(ax1, bx1), 0.0f);
            const float ih = fmaxf(fminf(ay2, by2) - fmaxf(ay1, by1), 0.0f);
            const float inter = iw * ih;
            const float area_a = fabsf((ax2 - ax1) * (ay2 - ay1));
            const float area_b = fabsf((bx2 - bx1) * (by2 - by1));
            const float iou = inter / (area_a + area_b - inter + 1e-6f);

            if (lane == 0) {                          // loop is wave-uniform
                a_nobj += 1.0f;
                a_cls  += (mx + __logf(e)) - lc;
                a_obj  += fmaxf(p0, 0.0f) - p0 * iou + __logf(1.0f + __expf(-fabsf(p0)));
                const float dx = sx - tx, dy = sy - ty;
                const float dw = pv[3] - __logf(tw / ax + 1e-16f);
                const float dh = pv[4] - __logf(th / ay + 1e-16f);
                a_box += dx * dx + dy * dy + dw * dw + dh * dh;
            }

            if (!h2) break;
            oc = oc1; w = w2; tv = tv2;
        }
    }

    // --- wave reduce (DPP+xor) -> LDS -> 1 atomic per block per accumulator ---
    a_nobj   = wave_sum(a_nobj);
    a_nnoobj = wave_sum(a_nnoobj);
    a_noobj  = wave_sum(a_noobj);
    a_obj    = wave_sum(a_obj);
    a_box    = wave_sum(a_box);
    a_cls    = wave_sum(a_cls);

    __shared__ float sdata[6][4];
    if (lane == 0) {
        sdata[0][wid] = a_nobj;
        sdata[1][wid] = a_nnoobj;
        sdata[2][wid] = a_noobj;
        sdata[3][wid] = a_obj;
        sdata[4][wid] = a_box;
        sdata[5][wid] = a_cls;
    }
    __syncthreads();
    if (threadIdx.x == 0) {
        float v0 = 0, v1 = 0, v2 = 0, v3 = 0, v4 = 0, v5 = 0;
        for (int w = 0; w < 4; ++w) {
            v0 += sdata[0][w]; v1 += sdata[1][w]; v2 += sdata[2][w];
            v3 += sdata[3][w]; v4 += sdata[4][w]; v5 += sdata[5][w];
        }
        atomicAdd(&acc[0], v0);
        atomicAdd(&acc[1], v1);
        atomicAdd(&acc[2], v2);
        atomicAdd(&acc[3], v3);
        atomicAdd(&acc[4], v4);
        atomicAdd(&acc[5], v5);
    }
}

__global__ void yolo_final(const float* __restrict__ acc, float* __restrict__ out) {
    const float n_obj   = fmaxf(acc[0], 1.0f);
    const float n_noobj = fmaxf(acc[1], 1.0f);
    out[0] = L_NOOBJ * acc[2] / n_noobj
           + L_OBJ   * acc[3] / n_obj
           + L_BOX   * acc[4] / (n_obj * 4.0f)
           + L_CLASS * acc[5] / n_obj;
}

extern "C" void kernel_launch(void* const* d_in, const int* in_sizes, int n_in,
                              void* d_out, int out_size, void* d_ws, size_t ws_size,
                              hipStream_t stream) {
    const float* pred = (const float*)d_in[0];
    const float* tgt  = (const float*)d_in[1];
    const float* anc  = (const float*)d_in[2];
    float* out = (float*)d_out;
    float* acc = (float*)d_ws;

    hipMemsetAsync(acc, 0, 6 * sizeof(float), stream);

    const int block = 256;
    const int nthreads = NCELL / G;                      // 64896
    const int grid = (nthreads + block - 1) / block;     // 254 blocks
    yolo_main<<<grid, block, 0, stream>>>(pred, (const float4*)pred, tgt, anc, acc);
    yolo_final<<<1, 1, 0, stream>>>(acc, out);
}

// Round 11
// 19.972 us; speedup vs baseline: 2.2514x; 2.2514x over previous
//
#include <hip/hip_runtime.h>

// YOLOv3 loss: B=32, A=3, S=52, C=80
constexpr int Aa = 3, Ss = 52, Cc = 80;
constexpr int NCELL = 32 * Aa * Ss * Ss;       // 259584 (divisible by 4)
constexpr int PSTR  = 5 + Cc;                  // 85 floats per cell
constexpr int G     = 4;                       // cells per thread
constexpr int NBLK  = (NCELL / G + 255) / 256; // 254 blocks
constexpr float L_CLASS = 1.0f, L_NOOBJ = 10.0f, L_OBJ = 1.0f, L_BOX = 10.0f;

// ---- DPP helpers: row_ror:k butterfly within 16-lane rows ----
__device__ __forceinline__ float dpp_ror1(float x) {
    return __builtin_bit_cast(float, __builtin_amdgcn_update_dpp(
        0, __builtin_bit_cast(int, x), 0x121, 0xf, 0xf, false));
}
__device__ __forceinline__ float dpp_ror2(float x) {
    return __builtin_bit_cast(float, __builtin_amdgcn_update_dpp(
        0, __builtin_bit_cast(int, x), 0x122, 0xf, 0xf, false));
}
__device__ __forceinline__ float dpp_ror4(float x) {
    return __builtin_bit_cast(float, __builtin_amdgcn_update_dpp(
        0, __builtin_bit_cast(int, x), 0x124, 0xf, 0xf, false));
}
__device__ __forceinline__ float dpp_ror8(float x) {
    return __builtin_bit_cast(float, __builtin_amdgcn_update_dpp(
        0, __builtin_bit_cast(int, x), 0x128, 0xf, 0xf, false));
}
__device__ __forceinline__ float wave_sum(float x) {
    x += dpp_ror1(x); x += dpp_ror2(x); x += dpp_ror4(x); x += dpp_ror8(x);
    x += __shfl_xor(x, 16, 64);
    x += __shfl_xor(x, 32, 64);
    return x;
}
__device__ __forceinline__ float wave_max(float x) {
    x = fmaxf(x, dpp_ror1(x)); x = fmaxf(x, dpp_ror2(x));
    x = fmaxf(x, dpp_ror4(x)); x = fmaxf(x, dpp_ror8(x));
    x = fmaxf(x, __shfl_xor(x, 16, 64));
    x = fmaxf(x, __shfl_xor(x, 32, 64));
    return x;
}
__device__ __forceinline__ float rdlane(float v, int l) {
    return __builtin_bit_cast(float, __builtin_amdgcn_readlane(__builtin_bit_cast(int, v), l));
}
__device__ __forceinline__ float bce0_fast(float x) {
    return fmaxf(x, 0.0f) + __logf(1.0f + __expf(-fabsf(x)));
}

// ws layout: float slots[NBLK][6]; every block writes its slot unconditionally
// each launch (no init needed, no atomics, deterministic).
// slot: [0]=n_obj [1]=n_noobj [2]=noobj_sum [3]=obj_sum [4]=box_sum [5]=cls_sum
__global__ void __launch_bounds__(256) yolo_main(const float* __restrict__ pred,
                                                 const float* __restrict__ tgt,
                                                 const float* __restrict__ anchors,
                                                 float* __restrict__ slots) {
    const int lane = threadIdx.x & 63;
    const int tid  = blockIdx.x * blockDim.x + threadIdx.x;
    const int base = tid * G;
    const bool valid = base < NCELL;

    float a_nobj = 0.f, a_nnoobj = 0.f, a_noobj = 0.f, a_obj = 0.f, a_box = 0.f, a_cls = 0.f;

    // --- front-load all independent loads (p0 gathers first: worst latency) ---
    float p0[G];
    float tf[6 * G];
    if (valid) {
        #pragma unroll
        for (int g = 0; g < G; ++g) p0[g] = pred[(size_t)(base + g) * PSTR];
        const float4* tp = reinterpret_cast<const float4*>(tgt + (size_t)base * 6);
        #pragma unroll
        for (int i = 0; i < 6; ++i) {
            float4 v = tp[i];
            tf[4 * i] = v.x; tf[4 * i + 1] = v.y; tf[4 * i + 2] = v.z; tf[4 * i + 3] = v.w;
        }
    }

    #pragma unroll
    for (int g = 0; g < G; ++g) {
        const int cell = base + g;
        const float t0  = valid ? tf[g * 6] : -1.0f;
        const float p0g = valid ? p0[g] : 0.0f;
        const bool is_obj = (t0 == 1.0f);

        if (t0 == 0.0f) {
            a_nnoobj += 1.0f;
            a_noobj  += bce0_fast(p0g);
        }

        int clsg = 0;
        if (is_obj) {
            a_nobj += 1.0f;
            const float* p = pred + (size_t)cell * PSTR;
            const int a = (cell / (Ss * Ss)) % Aa;
            const float ax = anchors[2 * a], ay = anchors[2 * a + 1];

            float px = p[1], py = p[2], pw = p[3], ph = p[4];
            float tx = tf[g * 6 + 1], ty = tf[g * 6 + 2];
            float tw = tf[g * 6 + 3], th = tf[g * 6 + 4];

            float sx = 1.0f / (1.0f + __expf(-px));
            float sy = 1.0f / (1.0f + __expf(-py));
            float ew = __expf(pw) * ax;
            float eh = __expf(ph) * ay;

            float ax1 = sx - ew * 0.5f, ax2 = sx + ew * 0.5f;
            float ay1 = sy - eh * 0.5f, ay2 = sy + eh * 0.5f;
            float bx1 = tx - tw * 0.5f, bx2 = tx + tw * 0.5f;
            float by1 = ty - th * 0.5f, by2 = ty + th * 0.5f;
            float iw = fmaxf(fminf(ax2, bx2) - fmaxf(ax1, bx1), 0.0f);
            float ih = fmaxf(fminf(ay2, by2) - fmaxf(ay1, by1), 0.0f);
            float inter = iw * ih;
            float area_a = fabsf((ax2 - ax1) * (ay2 - ay1));
            float area_b = fabsf((bx2 - bx1) * (by2 - by1));
            float iou = inter / (area_a + area_b - inter + 1e-6f);

            a_obj += fmaxf(p0g, 0.0f) - p0g * iou + __logf(1.0f + __expf(-fabsf(p0g)));

            float dx = sx - tx, dy = sy - ty;
            float dw = pw - __logf(tw / ax + 1e-16f);
            float dh = ph - __logf(th / ay + 1e-16f);
            a_box += dx * dx + dy * dy + dw * dw + dh * dh;

            clsg = (int)tf[g * 6 + 5];
        }

        // --- wave-parallel class CE, 2-deep pipelined row prefetch ---
        unsigned long long m = __ballot(is_obj);
        if (m) {
            int src0 = __ffsll(m) - 1; m &= m - 1;
            int cl0 = __builtin_amdgcn_readlane(clsg, src0);
            const int oc0 = __builtin_amdgcn_readlane(cell, src0);
            const float* r0 = pred + (size_t)oc0 * PSTR + 5;
            float v0 = r0[lane];
            float v1 = (lane < 16) ? r0[64 + lane] : -INFINITY;
            while (true) {
                // prefetch next obj row while reducing current
                int src1 = -1, cl1 = 0;
                float w0 = 0.f, w1 = -INFINITY;
                if (m) {
                    src1 = __ffsll(m) - 1; m &= m - 1;
                    cl1 = __builtin_amdgcn_readlane(clsg, src1);
                    const int oc1 = __builtin_amdgcn_readlane(cell, src1);
                    const float* r1 = pred + (size_t)oc1 * PSTR + 5;
                    w0 = r1[lane];
                    w1 = (lane < 16) ? r1[64 + lane] : -INFINITY;
                }
                float mx = wave_max(fmaxf(v0, v1));
                float e  = wave_sum(__expf(v0 - mx) + ((lane < 16) ? __expf(v1 - mx) : 0.0f));
                float lc = (cl0 < 64) ? rdlane(v0, cl0) : rdlane(v1, cl0 - 64);
                if (lane == src0) a_cls += (mx + __logf(e)) - lc;
                if (src1 < 0) break;
                src0 = src1; cl0 = cl1; v0 = w0; v1 = w1;
            }
        }
    }

    // --- wave reduce (DPP+xor) -> LDS -> per-block slot write (no atomics) ---
    a_nobj   = wave_sum(a_nobj);
    a_nnoobj = wave_sum(a_nnoobj);
    a_noobj  = wave_sum(a_noobj);
    a_obj    = wave_sum(a_obj);
    a_box    = wave_sum(a_box);
    a_cls    = wave_sum(a_cls);

    __shared__ float sdata[6][4];
    const int wid = threadIdx.x >> 6;
    if (lane == 0) {
        sdata[0][wid] = a_nobj;
        sdata[1][wid] = a_nnoobj;
        sdata[2][wid] = a_noobj;
        sdata[3][wid] = a_obj;
        sdata[4][wid] = a_box;
        sdata[5][wid] = a_cls;
    }
    __syncthreads();
    if (threadIdx.x < 6) {     // thread k writes slot component k (coalesced-ish, 6 stores)
        const int k = threadIdx.x;
        slots[(size_t)blockIdx.x * 6 + k] =
            sdata[k][0] + sdata[k][1] + sdata[k][2] + sdata[k][3];
    }
}

// one wave reduces all NBLK slots (6 KB, L2-hot)
__global__ void __launch_bounds__(64) yolo_final(const float* __restrict__ slots,
                                                 float* __restrict__ out) {
    float s[6] = {0.f, 0.f, 0.f, 0.f, 0.f, 0.f};
    for (int b = threadIdx.x; b < NBLK; b += 64) {
        #pragma unroll
        for (int k = 0; k < 6; ++k) s[k] += slots[(size_t)b * 6 + k];
    }
    #pragma unroll
    for (int k = 0; k < 6; ++k) s[k] = wave_sum(s[k]);

    if (threadIdx.x == 0) {
        const float n_obj   = fmaxf(s[0], 1.0f);
        const float n_noobj = fmaxf(s[1], 1.0f);
        out[0] = L_NOOBJ * s[2] / n_noobj
               + L_OBJ   * s[3] / n_obj
               + L_BOX   * s[4] / (n_obj * 4.0f)
               + L_CLASS * s[5] / n_obj;
    }
}

extern "C" void kernel_launch(void* const* d_in, const int* in_sizes, int n_in,
                              void* d_out, int out_size, void* d_ws, size_t ws_size,
                              hipStream_t stream) {
    const float* pred = (const float*)d_in[0];
    const float* tgt  = (const float*)d_in[1];
    const float* anc  = (const float*)d_in[2];
    float* out = (float*)d_out;
    float* slots = (float*)d_ws;   // NBLK*6 floats; fully overwritten every launch

    const int block = 256;
    yolo_main<<<NBLK, block, 0, stream>>>(pred, tgt, anc, slots);
    yolo_final<<<1, 64, 0, stream>>>(slots, out);
}

// Round 12
// 19.170 us; speedup vs baseline: 2.3456x; 1.0419x over previous
//
#include <hip/hip_runtime.h>

// YOLOv3 loss: B=32, A=3, S=52, C=80
constexpr int Aa = 3, Ss = 52, Cc = 80;
constexpr int NCELL = 32 * Aa * Ss * Ss;       // 259584 (divisible by 2)
constexpr int PSTR  = 5 + Cc;                  // 85 floats per cell
constexpr int G     = 2;                       // cells per thread (R12: was 4)
constexpr int NBLK  = (NCELL / G + 255) / 256; // 507 blocks -> ~2 blocks/CU
constexpr float L_CLASS = 1.0f, L_NOOBJ = 10.0f, L_OBJ = 1.0f, L_BOX = 10.0f;

// ---- DPP helpers: row_ror:k butterfly within 16-lane rows ----
__device__ __forceinline__ float dpp_ror1(float x) {
    return __builtin_bit_cast(float, __builtin_amdgcn_update_dpp(
        0, __builtin_bit_cast(int, x), 0x121, 0xf, 0xf, false));
}
__device__ __forceinline__ float dpp_ror2(float x) {
    return __builtin_bit_cast(float, __builtin_amdgcn_update_dpp(
        0, __builtin_bit_cast(int, x), 0x122, 0xf, 0xf, false));
}
__device__ __forceinline__ float dpp_ror4(float x) {
    return __builtin_bit_cast(float, __builtin_amdgcn_update_dpp(
        0, __builtin_bit_cast(int, x), 0x124, 0xf, 0xf, false));
}
__device__ __forceinline__ float dpp_ror8(float x) {
    return __builtin_bit_cast(float, __builtin_amdgcn_update_dpp(
        0, __builtin_bit_cast(int, x), 0x128, 0xf, 0xf, false));
}
__device__ __forceinline__ float wave_sum(float x) {
    x += dpp_ror1(x); x += dpp_ror2(x); x += dpp_ror4(x); x += dpp_ror8(x);
    x += __shfl_xor(x, 16, 64);
    x += __shfl_xor(x, 32, 64);
    return x;
}
__device__ __forceinline__ float wave_max(float x) {
    x = fmaxf(x, dpp_ror1(x)); x = fmaxf(x, dpp_ror2(x));
    x = fmaxf(x, dpp_ror4(x)); x = fmaxf(x, dpp_ror8(x));
    x = fmaxf(x, __shfl_xor(x, 16, 64));
    x = fmaxf(x, __shfl_xor(x, 32, 64));
    return x;
}
__device__ __forceinline__ float rdlane(float v, int l) {
    return __builtin_bit_cast(float, __builtin_amdgcn_readlane(__builtin_bit_cast(int, v), l));
}
__device__ __forceinline__ float bce0_fast(float x) {
    return fmaxf(x, 0.0f) + __logf(1.0f + __expf(-fabsf(x)));
}

// ws layout: float slots[NBLK][6]; every block writes its slot unconditionally
// each launch (no init needed, no atomics, deterministic).
// slot: [0]=n_obj [1]=n_noobj [2]=noobj_sum [3]=obj_sum [4]=box_sum [5]=cls_sum
__global__ void __launch_bounds__(256) yolo_main(const float* __restrict__ pred,
                                                 const float* __restrict__ tgt,
                                                 const float* __restrict__ anchors,
                                                 float* __restrict__ slots) {
    const int lane = threadIdx.x & 63;
    const int tid  = blockIdx.x * blockDim.x + threadIdx.x;
    const int base = tid * G;
    const bool valid = base < NCELL;

    float a_nobj = 0.f, a_nnoobj = 0.f, a_noobj = 0.f, a_obj = 0.f, a_box = 0.f, a_cls = 0.f;

    // --- front-load all independent loads (p0 gathers first: worst latency) ---
    float p0[G];
    float tf[6 * G];   // 2 cells x 6 target floats via 3 aligned float4 loads
    if (valid) {
        #pragma unroll
        for (int g = 0; g < G; ++g) p0[g] = pred[(size_t)(base + g) * PSTR];
        const float4* tp = reinterpret_cast<const float4*>(tgt + (size_t)base * 6);
        #pragma unroll
        for (int i = 0; i < 3; ++i) {
            float4 v = tp[i];
            tf[4 * i] = v.x; tf[4 * i + 1] = v.y; tf[4 * i + 2] = v.z; tf[4 * i + 3] = v.w;
        }
    }

    #pragma unroll
    for (int g = 0; g < G; ++g) {
        const int cell = base + g;
        const float t0  = valid ? tf[g * 6] : -1.0f;
        const float p0g = valid ? p0[g] : 0.0f;
        const bool is_obj = (t0 == 1.0f);

        if (t0 == 0.0f) {
            a_nnoobj += 1.0f;
            a_noobj  += bce0_fast(p0g);
        }

        int clsg = 0;
        if (is_obj) {
            a_nobj += 1.0f;
            const float* p = pred + (size_t)cell * PSTR;
            const int a = (cell / (Ss * Ss)) % Aa;
            const float ax = anchors[2 * a], ay = anchors[2 * a + 1];

            float px = p[1], py = p[2], pw = p[3], ph = p[4];
            float tx = tf[g * 6 + 1], ty = tf[g * 6 + 2];
            float tw = tf[g * 6 + 3], th = tf[g * 6 + 4];

            float sx = 1.0f / (1.0f + __expf(-px));
            float sy = 1.0f / (1.0f + __expf(-py));
            float ew = __expf(pw) * ax;
            float eh = __expf(ph) * ay;

            float ax1 = sx - ew * 0.5f, ax2 = sx + ew * 0.5f;
            float ay1 = sy - eh * 0.5f, ay2 = sy + eh * 0.5f;
            float bx1 = tx - tw * 0.5f, bx2 = tx + tw * 0.5f;
            float by1 = ty - th * 0.5f, by2 = ty + th * 0.5f;
            float iw = fmaxf(fminf(ax2, bx2) - fmaxf(ax1, bx1), 0.0f);
            float ih = fmaxf(fminf(ay2, by2) - fmaxf(ay1, by1), 0.0f);
            float inter = iw * ih;
            float area_a = fabsf((ax2 - ax1) * (ay2 - ay1));
            float area_b = fabsf((bx2 - bx1) * (by2 - by1));
            float iou = inter / (area_a + area_b - inter + 1e-6f);

            a_obj += fmaxf(p0g, 0.0f) - p0g * iou + __logf(1.0f + __expf(-fabsf(p0g)));

            float dx = sx - tx, dy = sy - ty;
            float dw = pw - __logf(tw / ax + 1e-16f);
            float dh = ph - __logf(th / ay + 1e-16f);
            a_box += dx * dx + dy * dy + dw * dw + dh * dh;

            clsg = (int)tf[g * 6 + 5];
        }

        // --- wave-parallel class CE, 2-deep pipelined row prefetch ---
        unsigned long long m = __ballot(is_obj);
        if (m) {
            int src0 = __ffsll(m) - 1; m &= m - 1;
            int cl0 = __builtin_amdgcn_readlane(clsg, src0);
            const int oc0 = __builtin_amdgcn_readlane(cell, src0);
            const float* r0 = pred + (size_t)oc0 * PSTR + 5;
            float v0 = r0[lane];
            float v1 = (lane < 16) ? r0[64 + lane] : -INFINITY;
            while (true) {
                // prefetch next obj row while reducing current
                int src1 = -1, cl1 = 0;
                float w0 = 0.f, w1 = -INFINITY;
                if (m) {
                    src1 = __ffsll(m) - 1; m &= m - 1;
                    cl1 = __builtin_amdgcn_readlane(clsg, src1);
                    const int oc1 = __builtin_amdgcn_readlane(cell, src1);
                    const float* r1 = pred + (size_t)oc1 * PSTR + 5;
                    w0 = r1[lane];
                    w1 = (lane < 16) ? r1[64 + lane] : -INFINITY;
                }
                float mx = wave_max(fmaxf(v0, v1));
                float e  = wave_sum(__expf(v0 - mx) + ((lane < 16) ? __expf(v1 - mx) : 0.0f));
                float lc = (cl0 < 64) ? rdlane(v0, cl0) : rdlane(v1, cl0 - 64);
                if (lane == src0) a_cls += (mx + __logf(e)) - lc;
                if (src1 < 0) break;
                src0 = src1; cl0 = cl1; v0 = w0; v1 = w1;
            }
        }
    }

    // --- wave reduce (DPP+xor) -> LDS -> per-block slot write (no atomics) ---
    a_nobj   = wave_sum(a_nobj);
    a_nnoobj = wave_sum(a_nnoobj);
    a_noobj  = wave_sum(a_noobj);
    a_obj    = wave_sum(a_obj);
    a_box    = wave_sum(a_box);
    a_cls    = wave_sum(a_cls);

    __shared__ float sdata[6][4];
    const int wid = threadIdx.x >> 6;
    if (lane == 0) {
        sdata[0][wid] = a_nobj;
        sdata[1][wid] = a_nnoobj;
        sdata[2][wid] = a_noobj;
        sdata[3][wid] = a_obj;
        sdata[4][wid] = a_box;
        sdata[5][wid] = a_cls;
    }
    __syncthreads();
    if (threadIdx.x < 6) {     // thread k writes slot component k
        const int k = threadIdx.x;
        slots[(size_t)blockIdx.x * 6 + k] =
            sdata[k][0] + sdata[k][1] + sdata[k][2] + sdata[k][3];
    }
}

// one wave reduces all NBLK slots (12 KB, L2-hot)
__global__ void __launch_bounds__(64) yolo_final(const float* __restrict__ slots,
                                                 float* __restrict__ out) {
    float s[6] = {0.f, 0.f, 0.f, 0.f, 0.f, 0.f};
    for (int b = threadIdx.x; b < NBLK; b += 64) {
        #pragma unroll
        for (int k = 0; k < 6; ++k) s[k] += slots[(size_t)b * 6 + k];
    }
    #pragma unroll
    for (int k = 0; k < 6; ++k) s[k] = wave_sum(s[k]);

    if (threadIdx.x == 0) {
        const float n_obj   = fmaxf(s[0], 1.0f);
        const float n_noobj = fmaxf(s[1], 1.0f);
        out[0] = L_NOOBJ * s[2] / n_noobj
               + L_OBJ   * s[3] / n_obj
               + L_BOX   * s[4] / (n_obj * 4.0f)
               + L_CLASS * s[5] / n_obj;
    }
}

extern "C" void kernel_launch(void* const* d_in, const int* in_sizes, int n_in,
                              void* d_out, int out_size, void* d_ws, size_t ws_size,
                              hipStream_t stream) {
    const float* pred = (const float*)d_in[0];
    const float* tgt  = (const float*)d_in[1];
    const float* anc  = (const float*)d_in[2];
    float* out = (float*)d_out;
    float* slots = (float*)d_ws;   // NBLK*6 floats; fully overwritten every launch

    const int block = 256;
    yolo_main<<<NBLK, block, 0, stream>>>(pred, tgt, anc, slots);
    yolo_final<<<1, 64, 0, stream>>>(slots, out);
}